// Round 9
// baseline (98.768 us; speedup 1.0000x reference)
//
#include <hip/hip_runtime.h>
#include <hip/hip_bf16.h>
#include <cstddef>

#define B_ 32
#define T_ 128
#define N_ 200
#define FI_ 32
#define FO_ 64
#define K_ 3

typedef __attribute__((ext_vector_type(8))) short short8;
typedef __attribute__((ext_vector_type(8))) unsigned short ushort8;
typedef __attribute__((ext_vector_type(4))) float f32x4;

// LDS: A only. Row stride 40 ushorts = 80B -> max 2-way bank aliasing (free).
#define AROW_ 40
#define A_ROWS_ (T_ + 2)            // t = -1 .. 128, zero-padded edges

__device__ __forceinline__ unsigned short f2bf(float f) {
    union { __hip_bfloat16 h; unsigned short u; } cv;
    cv.h = __float2bfloat16(f);
    return cv.u;
}

// One-shot: w[n,f,i,k] fp32 -> wbf[n][tap][f][i] bf16 (MFMA B-frag layout).
// Thread = (n, f, i-octet): 4x more parallel than R8's version (200 blocks,
// short serial chain) so it stops taxing the critical path.
__global__ void conv_prep(const float* __restrict__ w,
                          unsigned short* __restrict__ wbf) {
    const int idx = blockIdx.x * 256 + threadIdx.x;
    if (idx >= N_ * FO_ * 4) return;
    const int q  = idx & 3;          // i-octet (8 channels)
    const int nf = idx >> 2;         // (n, f)
    const int n = nf >> 6, f = nf & 63;

    const float* wp = w + (size_t)nf * (FI_ * K_) + (size_t)q * 8 * K_;  // 24 floats
    float v[24];
    #pragma unroll
    for (int j = 0; j < 6; ++j) {
        const float4 t4 = *reinterpret_cast<const float4*>(&wp[j * 4]);
        v[j*4+0] = t4.x; v[j*4+1] = t4.y; v[j*4+2] = t4.z; v[j*4+3] = t4.w;
    }
    #pragma unroll
    for (int tap = 0; tap < K_; ++tap) {
        ushort8 u;
        #pragma unroll
        for (int e = 0; e < 8; ++e) u[e] = f2bf(v[e * K_ + tap]);
        *reinterpret_cast<ushort8*>(
            &wbf[(((size_t)n * K_ + tap) * FO_ + f) * FI_ + q * 8]) = u;
    }
}

// R3 skeleton, W-LDS removed: one block per (b, n), 4 waves x 32 t-rows.
// A staged once in LDS (5.3KB); B-frags per tap stream from wbf (L2-resident
// 2.46MB, 1KB/instr coalesced). Per-tap bfr[4] keeps live VGPR ~75 <= 85 cap.
template <bool PREW>
__global__ __launch_bounds__(256, 6) void conv_main(
    const float* __restrict__ x, const float* __restrict__ w,
    const unsigned short* __restrict__ wbf,
    const float* __restrict__ bias, float* __restrict__ out)
{
    __shared__ __align__(16) unsigned short lds[A_ROWS_ * AROW_];  // 5280 B

    const int bid = blockIdx.x;
    const int b = bid & 31;    // b-fastest: 32 consecutive blocks share n (R3)
    const int n = bid >> 5;
    const int tid = threadIdx.x;
    const int lane = tid & 63;
    const int wv = tid >> 6;
    const int row16 = lane & 15;
    const int grp = lane >> 4;

    // ---- stage x[b, t, n, 0:32] for t = -1..128 as bf16 into LDS ----
    const float* xb = x + ((size_t)b * T_ * N_ + n) * FI_;
    for (int s = tid; s < A_ROWS_ * 4; s += 256) {
        const int rr = s >> 2, q = s & 3;
        const int t = rr - 1;
        ushort8 u = (ushort8)0;
        if (t >= 0 && t < T_) {
            const float4 v0 = *reinterpret_cast<const float4*>(
                &xb[(size_t)t * N_ * FI_ + q * 8]);
            const float4 v1 = *reinterpret_cast<const float4*>(
                &xb[(size_t)t * N_ * FI_ + q * 8 + 4]);
            u[0] = f2bf(v0.x); u[1] = f2bf(v0.y); u[2] = f2bf(v0.z); u[3] = f2bf(v0.w);
            u[4] = f2bf(v1.x); u[5] = f2bf(v1.y); u[6] = f2bf(v1.z); u[7] = f2bf(v1.w);
        }
        *reinterpret_cast<ushort8*>(&lds[rr * AROW_ + q * 8]) = u;
    }

    __syncthreads();

    f32x4 acc[2][4];
    #pragma unroll
    for (int m = 0; m < 2; ++m)
        #pragma unroll
        for (int j = 0; j < 4; ++j)
            acc[m][j] = (f32x4){0.f, 0.f, 0.f, 0.f};

    // out[t] += x[t + k - 1] @ W_k ; LDS A-row = t + k (t offset +1 for pad)
    #pragma unroll
    for (int k = 0; k < K_; ++k) {
        const short8 a0 = *reinterpret_cast<const short8*>(
            &lds[(wv * 32 + 0  + row16 + k) * AROW_ + grp * 8]);
        const short8 a1 = *reinterpret_cast<const short8*>(
            &lds[(wv * 32 + 16 + row16 + k) * AROW_ + grp * 8]);
        short8 bfr[4];
        if constexpr (PREW) {
            #pragma unroll
            for (int j = 0; j < 4; ++j)
                bfr[j] = *reinterpret_cast<const short8*>(
                    &wbf[(((size_t)n * K_ + k) * FO_ + j * 16 + row16) * FI_ + grp * 8]);
        } else {
            #pragma unroll
            for (int j = 0; j < 4; ++j) {
                const float* wp = &w[((size_t)(n * FO_ + j * 16 + row16)) * (FI_ * K_)
                                     + grp * 8 * K_];
                ushort8 u;
                #pragma unroll
                for (int e = 0; e < 8; ++e) u[e] = f2bf(wp[e * K_ + k]);
                union { ushort8 u8; short8 s8; } cv; cv.u8 = u;
                bfr[j] = cv.s8;
            }
        }
        #pragma unroll
        for (int j = 0; j < 4; ++j) {
            acc[0][j] = __builtin_amdgcn_mfma_f32_16x16x32_bf16(a0, bfr[j], acc[0][j], 0, 0, 0);
            acc[1][j] = __builtin_amdgcn_mfma_f32_16x16x32_bf16(a1, bfr[j], acc[1][j], 0, 0, 0);
        }
    }

    // ---- epilogue: C/D layout col=lane&15 -> f, row=grp*4+r -> t (m89) ----
    #pragma unroll
    for (int j = 0; j < 4; ++j) {
        const float bv = bias[n * FO_ + j * 16 + row16];
        #pragma unroll
        for (int m = 0; m < 2; ++m) {
            #pragma unroll
            for (int r = 0; r < 4; ++r) {
                const int t = wv * 32 + m * 16 + grp * 4 + r;
                out[(((size_t)b * T_ + t) * N_ + n) * FO_ + j * 16 + row16] =
                    acc[m][j][r] + bv;
            }
        }
    }
}

extern "C" void kernel_launch(void* const* d_in, const int* in_sizes, int n_in,
                              void* d_out, int out_size, void* d_ws, size_t ws_size,
                              hipStream_t stream) {
    const float* x    = (const float*)d_in[0];
    const float* w    = (const float*)d_in[1];
    const float* bias = (const float*)d_in[2];
    float* out = (float*)d_out;

    const size_t W_BF_BYTES = (size_t)N_ * K_ * FO_ * FI_ * 2;  // 2.46 MB
    const int grid = B_ * N_;  // 6400 blocks: (n, b), b fastest (R3 order)

    if (ws_size >= W_BF_BYTES) {
        unsigned short* wbf = (unsigned short*)d_ws;
        conv_prep<<<(N_ * FO_ * 4 + 255) / 256, 256, 0, stream>>>(w, wbf);
        conv_main<true><<<grid, 256, 0, stream>>>(x, w, wbf, bias, out);
    } else {
        conv_main<false><<<grid, 256, 0, stream>>>(x, w, nullptr, bias, out);
    }
}

// Round 10
// 82.083 us; speedup vs baseline: 1.2033x; 1.2033x over previous
//
#include <hip/hip_runtime.h>
#include <hip/hip_bf16.h>
#include <cstddef>

#define B_ 32
#define T_ 128
#define N_ 200
#define FI_ 32
#define FO_ 64
#define K_ 3

typedef __attribute__((ext_vector_type(8))) short short8;            // 8 bf16 (4 VGPRs)
typedef __attribute__((ext_vector_type(8))) unsigned short ushort8;
typedef __attribute__((ext_vector_type(4))) float f32x4;

// LDS layout (ushort units). Row stride 40 ushorts = 80 B: banks advance by
// 20 mod 32 per row -> 16 consecutive rows give 2-way aliasing max (free, m136).
#define AROW_ 40
#define A_ROWS_ (T_ + 2)            // t = -1 .. 128, zero-padded edges
#define B_OFF_ (A_ROWS_ * AROW_)    // 5200
#define BROW_ 40
#define BK_SZ_ (FO_ * BROW_)        // 2560 ushorts per tap k

__device__ __forceinline__ unsigned short f2bf(float f) {
    union { __hip_bfloat16 h; unsigned short u; } cv;
    cv.h = __float2bfloat16(f);
    return cv.u;
}

// EXACT R3 kernel (78.6 us): one block per (b, n), full T=128 x all 64 f.
// 4 waves, each owns 32 t-rows; 3 taps x 2 m-frags x 4 n-frags = 24 mfma/wave.
// SINGLE change vs R3: grid order n-fastest. Since 200 % 8 == 0, XCD = n % 8:
// all 32 b-blocks of a given n run on ONE XCD -> W slice L2-resident (615KB/XCD),
// and resident blocks span all 200 n -> concurrent epilogues cover contiguous
// 51.2KB [n][f] rows per (b,t) for DRAM write page locality.
__global__ __launch_bounds__(256, 4) void multiconv_mfma(
    const float* __restrict__ x, const float* __restrict__ w,
    const float* __restrict__ bias, float* __restrict__ out)
{
    __shared__ __align__(16) unsigned short lds[B_OFF_ + K_ * BK_SZ_];  // 25760 B

    const int bid = blockIdx.x;
    const int n = bid % N_;    // n-fastest (the one change vs R3)
    const int b = bid / N_;
    const int tid = threadIdx.x;
    const int lane = tid & 63;
    const int wv = tid >> 6;

    // ---- stage x[b, t, n, 0:32] for t = -1..128 as bf16 (rows of 32ch) ----
    const float* xb = x + ((size_t)b * T_ * N_ + n) * FI_;
    for (int s = tid; s < A_ROWS_ * 4; s += 256) {
        const int rr = s >> 2, q = s & 3;   // rr: LDS row, q: 8-channel slot
        const int t = rr - 1;
        ushort8 u = (ushort8)0;
        if (t >= 0 && t < T_) {
            const float4 v0 = *reinterpret_cast<const float4*>(
                &xb[(size_t)t * N_ * FI_ + q * 8]);
            const float4 v1 = *reinterpret_cast<const float4*>(
                &xb[(size_t)t * N_ * FI_ + q * 8 + 4]);
            u[0] = f2bf(v0.x); u[1] = f2bf(v0.y); u[2] = f2bf(v0.z); u[3] = f2bf(v0.w);
            u[4] = f2bf(v1.x); u[5] = f2bf(v1.y); u[6] = f2bf(v1.z); u[7] = f2bf(v1.w);
        }
        *reinterpret_cast<ushort8*>(&lds[rr * AROW_ + q * 8]) = u;
    }

    // ---- stage w[n,f,i,k] -> B_lds[k][f][i] bf16 (i contiguous per lane) ----
    {
        const int f = tid >> 2;
        const int i0 = (tid & 3) * 8;
        const float* wp = w + ((size_t)n * FO_ + f) * (FI_ * K_) + (size_t)i0 * K_;
        float v[24];
        #pragma unroll
        for (int j = 0; j < 6; ++j) {
            const float4 t4 = *reinterpret_cast<const float4*>(&wp[j * 4]);
            v[j*4+0] = t4.x; v[j*4+1] = t4.y; v[j*4+2] = t4.z; v[j*4+3] = t4.w;
        }
        #pragma unroll
        for (int k = 0; k < K_; ++k) {
            ushort8 u;
            #pragma unroll
            for (int j = 0; j < 8; ++j) u[j] = f2bf(v[j * K_ + k]);
            *reinterpret_cast<ushort8*>(&lds[B_OFF_ + k * BK_SZ_ + f * BROW_ + i0]) = u;
        }
    }

    __syncthreads();

    f32x4 acc[2][4];
    #pragma unroll
    for (int m = 0; m < 2; ++m)
        #pragma unroll
        for (int j = 0; j < 4; ++j)
            acc[m][j] = (f32x4){0.f, 0.f, 0.f, 0.f};

    const int row16 = lane & 15;
    const int grp = lane >> 4;

    // out[t] += x[t + k - 1] @ W_k ; LDS A-row = t + k (t offset by +1 for pad)
    #pragma unroll
    for (int k = 0; k < K_; ++k) {
        const short8 a0 = *reinterpret_cast<const short8*>(
            &lds[(wv * 32 + 0  + row16 + k) * AROW_ + grp * 8]);
        const short8 a1 = *reinterpret_cast<const short8*>(
            &lds[(wv * 32 + 16 + row16 + k) * AROW_ + grp * 8]);
        #pragma unroll
        for (int j = 0; j < 4; ++j) {
            const short8 bf = *reinterpret_cast<const short8*>(
                &lds[B_OFF_ + k * BK_SZ_ + (j * 16 + row16) * BROW_ + grp * 8]);
            acc[0][j] = __builtin_amdgcn_mfma_f32_16x16x32_bf16(a0, bf, acc[0][j], 0, 0, 0);
            acc[1][j] = __builtin_amdgcn_mfma_f32_16x16x32_bf16(a1, bf, acc[1][j], 0, 0, 0);
        }
    }

    // ---- epilogue: C/D layout col=lane&15, row=(lane>>4)*4+reg (m89) ----
    #pragma unroll
    for (int j = 0; j < 4; ++j) {
        const float bv = bias[n * FO_ + j * 16 + row16];
        #pragma unroll
        for (int m = 0; m < 2; ++m) {
            #pragma unroll
            for (int r = 0; r < 4; ++r) {
                const int t = wv * 32 + m * 16 + grp * 4 + r;
                out[(((size_t)b * T_ + t) * N_ + n) * FO_ + j * 16 + row16] =
                    acc[m][j][r] + bv;
            }
        }
    }
}

extern "C" void kernel_launch(void* const* d_in, const int* in_sizes, int n_in,
                              void* d_out, int out_size, void* d_ws, size_t ws_size,
                              hipStream_t stream) {
    const float* x    = (const float*)d_in[0];
    const float* w    = (const float*)d_in[1];
    const float* bias = (const float*)d_in[2];
    float* out = (float*)d_out;

    const int grid = B_ * N_;  // 6400 blocks: (b, n), n fastest
    multiconv_mfma<<<grid, 256, 0, stream>>>(x, w, bias, out);
}